// Round 8
// baseline (68.814 us; speedup 1.0000x reference)
//
#include <hip/hip_runtime.h>
#include <hip/hip_bf16.h>
#include <cstdint>
#include <cstddef>

typedef __attribute__((ext_vector_type(8))) short bf16x8;
typedef __attribute__((ext_vector_type(4))) float f32x4;
typedef __attribute__((ext_vector_type(4))) unsigned int u32x4;

#define T_DIM 2048
#define C_DIM 1024
#define B_DIM 8
#define NEG_BIG (-3.0e38f)

__device__ __forceinline__ unsigned short f2bf(float f) {
  union { __hip_bfloat16 h; unsigned short u; } cv;
  cv.h = __float2bfloat16(f);
  return cv.u;
}
__device__ __forceinline__ f32x4 mfma16(bf16x8 a, bf16x8 b, f32x4 c) {
  return __builtin_amdgcn_mfma_f32_16x16x32_bf16(a, b, c, 0, 0, 0);
}

// ---------------------------------------------------------------------------
// prep_w: W [1024][64] f32 -> Wt [3][64][1024] bf16 (transposed; Wq scaled 1/8)
// (unchanged)
// ---------------------------------------------------------------------------
__global__ __launch_bounds__(256) void prep_w(
    const float* __restrict__ Wq, const float* __restrict__ Wk,
    const float* __restrict__ Wv, unsigned short* __restrict__ Wt)
{
  const int mtx = blockIdx.x >> 4;
  const int k0  = (blockIdx.x & 15) * 64;
  const float* W = (mtx == 0) ? Wq : ((mtx == 1) ? Wk : Wv);
  const float scale = (mtx == 0) ? 0.125f : 1.0f;
  __shared__ float Ws[64][65];
  const int t = threadIdx.x;
#pragma unroll
  for (int j = 0; j < 4; ++j) {
    int r = (t >> 4) + 16 * j;
    int c = (t & 15) * 4;
    union { float4 f4; float f[4]; } uv;
    uv.f4 = *(const float4*)&W[(size_t)(k0 + r) * 64 + c];
#pragma unroll
    for (int jj = 0; jj < 4; ++jj) Ws[c + jj][r] = uv.f[jj] * scale;
  }
  __syncthreads();
#pragma unroll
  for (int q = 0; q < 2; ++q) {
    int g_ = t + 256 * q;
    int d  = g_ >> 3;
    int ko = (g_ & 7) * 8;
    union { unsigned short u[8]; u32x4 v; } pk;
#pragma unroll
    for (int jj = 0; jj < 8; ++jj) pk.u[jj] = f2bf(Ws[d][ko + jj]);
    *(u32x4*)&Wt[((size_t)mtx * 64 + d) * C_DIM + k0 + ko] = pk.v;
  }
}

// ---------------------------------------------------------------------------
// qkv_proj_mfma: round-5 version (verified ~22 us). Unchanged.
// ---------------------------------------------------------------------------
__global__ __launch_bounds__(256) void qkv_proj_mfma(
    const float* __restrict__ x,
    const unsigned short* __restrict__ Wt,
    const float* __restrict__ bq, const float* __restrict__ bk, const float* __restrict__ bv,
    unsigned short* __restrict__ Qb, unsigned short* __restrict__ Kb,
    unsigned short* __restrict__ VTb)
{
  __shared__ __align__(16) short Xs[64 * 64];
  __shared__ __align__(16) short Ws[3 * 64 * 64];
  __shared__ __align__(16) unsigned short VTs[64 * 72];

  const int tid = threadIdx.x;
  const int wv = tid >> 6, lane = tid & 63, g = lane >> 4, ln15 = lane & 15;
  const size_t m0 = (size_t)blockIdx.x * 64;

  f32x4 acc[4][3];
#pragma unroll
  for (int mt = 0; mt < 4; ++mt)
#pragma unroll
    for (int j = 0; j < 3; ++j) acc[mt][j] = (f32x4){0.f, 0.f, 0.f, 0.f};

  for (int kt = 0; kt < 16; ++kt) {
    __syncthreads();
#pragma unroll
    for (int q = 0; q < 4; ++q) {
      int g_ = tid + 256 * q;
      int r = g_ >> 4, c4 = (g_ & 15) * 4;
      union { float4 f4; float f[4]; } uv;
      uv.f4 = *(const float4*)&x[(m0 + r) * C_DIM + kt * 64 + c4];
      union { unsigned short u[4]; unsigned long long ll; } pk;
#pragma unroll
      for (int jj = 0; jj < 4; ++jj) pk.u[jj] = f2bf(uv.f[jj]);
      *(unsigned long long*)((char*)Xs + r * 128 + ((c4 * 2) ^ ((r & 7) << 4))) = pk.ll;
    }
#pragma unroll
    for (int mt = 0; mt < 3; ++mt)
#pragma unroll
      for (int q = 0; q < 2; ++q) {
        int g_ = tid + 256 * q;
        int d = g_ >> 3, ko = (g_ & 7) * 8;
        u32x4 v = *(const u32x4*)&Wt[((size_t)mt * 64 + d) * C_DIM + kt * 64 + ko];
        *(u32x4*)((char*)Ws + mt * 8192 + d * 128 + ((ko * 2) ^ ((d & 7) << 4))) = v;
      }
    __syncthreads();
#pragma unroll
    for (int kc = 0; kc < 2; ++kc) {
      bf16x8 a[4];
#pragma unroll
      for (int mt = 0; mt < 4; ++mt) {
        int xr = mt * 16 + ln15;
        a[mt] = *(const bf16x8*)((const char*)Xs + xr * 128 + ((kc * 64 + g * 16) ^ ((xr & 7) << 4)));
      }
#pragma unroll
      for (int j = 0; j < 3; ++j) {
        int ntg = wv * 3 + j;
        int mtx = ntg >> 2, nc = (ntg & 3) * 16;
        int wrow = nc + ln15;
        bf16x8 bb = *(const bf16x8*)((const char*)Ws + mtx * 8192 + wrow * 128 + ((kc * 64 + g * 16) ^ ((wrow & 7) << 4)));
#pragma unroll
        for (int mt = 0; mt < 4; ++mt)
          acc[mt][j] = mfma16(a[mt], bb, acc[mt][j]);
      }
    }
  }

  __syncthreads();
#pragma unroll
  for (int j = 0; j < 3; ++j) {
    int ntg = wv * 3 + j;
    int mtx = ntg >> 2, nc = (ntg & 3) * 16;
    if (mtx < 2) {
      const float* bias = (mtx == 0) ? bq : bk;
      unsigned short* Out = (mtx == 0) ? Qb : Kb;
      float bvv = bias[nc + ln15] * ((mtx == 0) ? 0.125f : 1.0f);
#pragma unroll
      for (int mt = 0; mt < 4; ++mt)
#pragma unroll
        for (int i = 0; i < 4; ++i)
          Out[(m0 + mt * 16 + 4 * g + i) * 64 + nc + ln15] = f2bf(acc[mt][j][i] + bvv);
    } else {
      float bvv = bv[nc + ln15];
#pragma unroll
      for (int mt = 0; mt < 4; ++mt)
#pragma unroll
        for (int i = 0; i < 4; ++i)
          VTs[(nc + ln15) * 72 + mt * 16 + 4 * g + i] = f2bf(acc[mt][j][i] + bvv);
    }
  }
  __syncthreads();
  {
    int d = tid >> 2, t8 = (tid & 3) * 16;
    u32x4 v0 = *(const u32x4*)&VTs[d * 72 + t8];
    u32x4 v1 = *(const u32x4*)&VTs[d * 72 + t8 + 8];
    size_t b = m0 >> 11, tloc = m0 & 2047;
    *(u32x4*)&VTb[(b * 64 + d) * T_DIM + tloc + t8] = v0;
    *(u32x4*)&VTb[(b * 64 + d) * T_DIM + tloc + t8 + 8] = v1;
  }
}

// ---------------------------------------------------------------------------
// attn_flash: barrier-free flash attention, now with K-fragment register
// double-buffer (named kA/kB sets, 2-unrolled steady state). QK^T(t) consumes
// K loaded one iteration earlier; V(t) issued at phase start and consumed
// after softmax (~300 cyc of cover). Only change vs round 7.
// ---------------------------------------------------------------------------
__global__ __launch_bounds__(256) void attn_flash(
    const unsigned short* __restrict__ Qb,   // [B*T][64] (pre-scaled 1/8)
    const unsigned short* __restrict__ Kb,   // [B*T][64]
    const unsigned short* __restrict__ VTb,  // [B][64][T]
    float* __restrict__ out)                 // [B*T][64] f32
{
  __shared__ __align__(16) short Ps[4][16 * 64];   // per-wave P slab, swizzled
  __shared__ __align__(16) float Zs[3][16 * 64];   // merge slabs (waves 1..3)
  __shared__ float Ml[3][16][2];

  const int tid  = threadIdx.x;
  const int wv   = tid >> 6;
  const int lane = tid & 63;
  const int g    = lane >> 4;
  const int ln15 = lane & 15;

  const int qt = 127 - (blockIdx.x >> 3);   // longest first (LPT)
  const int b  = blockIdx.x & 7;
  const int r0 = qt * 16;
  const int ntiles = (qt >> 2) + 1;

  const size_t bT = (size_t)b * T_DIM;

  bf16x8 qa[2];
  {
    const unsigned short* qp = Qb + (bT + r0 + ln15) * 64 + g * 8;
    qa[0] = *(const bf16x8*)qp;
    qa[1] = *(const bf16x8*)(qp + 32);
  }

  f32x4 acc[4];
#pragma unroll
  for (int nt = 0; nt < 4; ++nt) acc[nt] = (f32x4){0.f, 0.f, 0.f, 0.f};
  float m_[4], l_[4];
#pragma unroll
  for (int i = 0; i < 4; ++i) { m_[i] = NEG_BIG; l_[i] = 0.f; }

  char* myP = (char*)Ps[wv];

  auto loadK = [&](bf16x8 (&kf)[4][2], int it) {
    const int s0 = it * 64;
#pragma unroll
    for (int nt = 0; nt < 4; ++nt) {
      const unsigned short* kp = Kb + (bT + s0 + nt * 16 + ln15) * 64 + g * 8;
      kf[nt][0] = *(const bf16x8*)kp;
      kf[nt][1] = *(const bf16x8*)(kp + 32);
    }
  };
  auto loadV = [&](bf16x8 (&vf)[4][2], int it) {
    const int s0 = it * 64;
#pragma unroll
    for (int nt = 0; nt < 4; ++nt) {
      const unsigned short* vp = VTb + ((size_t)b * 64 + nt * 16 + ln15) * T_DIM + s0 + g * 8;
      vf[nt][0] = *(const bf16x8*)vp;
      vf[nt][1] = *(const bf16x8*)(vp + 32);
    }
  };
  auto step = [&](const bf16x8 (&kf)[4][2], const bf16x8 (&vf)[4][2], int it) {
    const int s0 = it * 64;
    // QK^T
    f32x4 sfr[4];
#pragma unroll
    for (int nt = 0; nt < 4; ++nt) {
      f32x4 a = (f32x4){0.f, 0.f, 0.f, 0.f};
      a = mfma16(qa[0], kf[nt][0], a);
      a = mfma16(qa[1], kf[nt][1], a);
      sfr[nt] = a;
    }
    // causal mask: tile fully unmasked only if s0+63 <= r0 (min row)
    if (s0 + 63 > r0) {
#pragma unroll
      for (int nt = 0; nt < 4; ++nt) {
        int colg = s0 + nt * 16 + ln15;
#pragma unroll
        for (int i = 0; i < 4; ++i) {
          int rowg = r0 + 4 * g + i;
          if (colg > rowg) sfr[nt][i] = NEG_BIG;
        }
      }
    }
    // online softmax (row = 4g+i; kv across 16 lanes x 4 nt frags)
    float mx[4], corr[4];
#pragma unroll
    for (int i = 0; i < 4; ++i)
      mx[i] = fmaxf(fmaxf(sfr[0][i], sfr[1][i]), fmaxf(sfr[2][i], sfr[3][i]));
#pragma unroll
    for (int i = 0; i < 4; ++i) {
#pragma unroll
      for (int off = 1; off < 16; off <<= 1)
        mx[i] = fmaxf(mx[i], __shfl_xor(mx[i], off));
      float mn = fmaxf(m_[i], mx[i]);
      corr[i] = __expf(m_[i] - mn);
      m_[i] = mn;
    }
#pragma unroll
    for (int nt = 0; nt < 4; ++nt)
#pragma unroll
      for (int i = 0; i < 4; ++i)
        sfr[nt][i] = __expf(sfr[nt][i] - m_[i]);
#pragma unroll
    for (int i = 0; i < 4; ++i) {
      float ps = sfr[0][i] + sfr[1][i] + sfr[2][i] + sfr[3][i];
#pragma unroll
      for (int off = 1; off < 16; off <<= 1)
        ps += __shfl_xor(ps, off);
      l_[i] = l_[i] * corr[i] + ps;
    }
#pragma unroll
    for (int nt = 0; nt < 4; ++nt)
#pragma unroll
      for (int i = 0; i < 4; ++i)
        acc[nt][i] *= corr[i];
    // P -> wave-private LDS (swizzled) -> A-fragments (wave-local, no barrier)
#pragma unroll
    for (int nt = 0; nt < 4; ++nt)
#pragma unroll
      for (int i = 0; i < 4; ++i) {
        int r_ = 4 * g + i;
        *(unsigned short*)(myP + r_ * 128 + ((((nt * 16 + ln15)) * 2) ^ ((r_ & 7) << 4))) = f2bf(sfr[nt][i]);
      }
    bf16x8 pa[2];
#pragma unroll
    for (int kc = 0; kc < 2; ++kc)
      pa[kc] = *(const bf16x8*)(myP + ln15 * 128 + ((kc * 64 + g * 16) ^ ((ln15 & 7) << 4)));
    // PV
#pragma unroll
    for (int nt = 0; nt < 4; ++nt) {
      acc[nt] = mfma16(pa[0], vf[nt][0], acc[nt]);
      acc[nt] = mfma16(pa[1], vf[nt][1], acc[nt]);
    }
  };

  // pipelined main loop: K prefetched one wave-iteration (4 tiles) ahead
  bf16x8 kA[4][2], kB[4][2], vf[4][2];
  if (wv < ntiles) loadK(kA, wv);
  for (int it = wv; it < ntiles; it += 8) {
    loadV(vf, it);
    if (it + 4 < ntiles) loadK(kB, it + 4);
    step(kA, vf, it);
    if (it + 4 < ntiles) {
      loadV(vf, it + 4);
      if (it + 8 < ntiles) loadK(kA, it + 8);
      step(kB, vf, it + 4);
    }
  }

  // 4-way merge (single barrier)
  if (wv > 0) {
#pragma unroll
    for (int nt = 0; nt < 4; ++nt)
#pragma unroll
      for (int i = 0; i < 4; ++i)
        Zs[wv - 1][(4 * g + i) * 64 + nt * 16 + ln15] = acc[nt][i];
    if (ln15 == 0) {
#pragma unroll
      for (int i = 0; i < 4; ++i) {
        Ml[wv - 1][4 * g + i][0] = m_[i];
        Ml[wv - 1][4 * g + i][1] = l_[i];
      }
    }
  }
  __syncthreads();
  if (wv == 0) {
    float mm[4], e0[4], ew[3][4], inv[4];
#pragma unroll
    for (int i = 0; i < 4; ++i) {
      mm[i] = m_[i];
#pragma unroll
      for (int w = 0; w < 3; ++w) mm[i] = fmaxf(mm[i], Ml[w][4 * g + i][0]);
      e0[i] = __expf(m_[i] - mm[i]);
      float lsum = l_[i] * e0[i];
#pragma unroll
      for (int w = 0; w < 3; ++w) {
        ew[w][i] = __expf(Ml[w][4 * g + i][0] - mm[i]);
        lsum += Ml[w][4 * g + i][1] * ew[w][i];
      }
      inv[i] = 1.0f / lsum;
    }
    float* ob = out + (bT + r0) * 64;
#pragma unroll
    for (int nt = 0; nt < 4; ++nt)
#pragma unroll
      for (int i = 0; i < 4; ++i) {
        float z = acc[nt][i] * e0[i];
#pragma unroll
        for (int w = 0; w < 3; ++w)
          z += Zs[w][(4 * g + i) * 64 + nt * 16 + ln15] * ew[w][i];
        ob[(size_t)(4 * g + i) * 64 + nt * 16 + ln15] = z * inv[i];
      }
  }
}

// ---------------------------------------------------------------------------
extern "C" void kernel_launch(void* const* d_in, const int* in_sizes, int n_in,
                              void* d_out, int out_size, void* d_ws, size_t ws_size,
                              hipStream_t stream)
{
  const float* x  = (const float*)d_in[0];
  const float* Wq = (const float*)d_in[1];
  const float* bq = (const float*)d_in[2];
  const float* Wk = (const float*)d_in[3];
  const float* bk = (const float*)d_in[4];
  const float* Wv = (const float*)d_in[5];
  const float* bv = (const float*)d_in[6];
  float* out = (float*)d_out;

  char* ws = (char*)d_ws;
  unsigned short* Wt  = (unsigned short*)(ws);                      // 384 KB
  unsigned short* Qb  = (unsigned short*)(ws + (1u << 19));         // 2 MB
  unsigned short* Kb  = (unsigned short*)(ws + (1u << 19) + (1u << 21));
  unsigned short* VTb = (unsigned short*)(ws + (1u << 19) + (2u << 21));

  prep_w<<<48, 256, 0, stream>>>(Wq, Wk, Wv, Wt);
  qkv_proj_mfma<<<256, 256, 0, stream>>>(x, Wt, bq, bk, bv, Qb, Kb, VTb);
  attn_flash<<<1024, 256, 0, stream>>>(Qb, Kb, VTb, out);
}

// Round 9
// 61.438 us; speedup vs baseline: 1.1201x; 1.1201x over previous
//
#include <hip/hip_runtime.h>
#include <hip/hip_bf16.h>
#include <cstdint>
#include <cstddef>

typedef __attribute__((ext_vector_type(8))) short bf16x8;
typedef __attribute__((ext_vector_type(4))) float f32x4;
typedef __attribute__((ext_vector_type(4))) unsigned int u32x4;

#define T_DIM 2048
#define C_DIM 1024
#define B_DIM 8
#define NEG_BIG (-3.0e38f)

__device__ __forceinline__ unsigned short f2bf(float f) {
  union { __hip_bfloat16 h; unsigned short u; } cv;
  cv.h = __float2bfloat16(f);
  return cv.u;
}
__device__ __forceinline__ f32x4 mfma16(bf16x8 a, bf16x8 b, f32x4 c) {
  return __builtin_amdgcn_mfma_f32_16x16x32_bf16(a, b, c, 0, 0, 0);
}

// ---------------------------------------------------------------------------
// prep_w: W [1024][64] f32 -> Wt [3][64][1024] bf16 (transposed; Wq scaled 1/8)
// (unchanged)
// ---------------------------------------------------------------------------
__global__ __launch_bounds__(256) void prep_w(
    const float* __restrict__ Wq, const float* __restrict__ Wk,
    const float* __restrict__ Wv, unsigned short* __restrict__ Wt)
{
  const int mtx = blockIdx.x >> 4;
  const int k0  = (blockIdx.x & 15) * 64;
  const float* W = (mtx == 0) ? Wq : ((mtx == 1) ? Wk : Wv);
  const float scale = (mtx == 0) ? 0.125f : 1.0f;
  __shared__ float Ws[64][65];
  const int t = threadIdx.x;
#pragma unroll
  for (int j = 0; j < 4; ++j) {
    int r = (t >> 4) + 16 * j;
    int c = (t & 15) * 4;
    union { float4 f4; float f[4]; } uv;
    uv.f4 = *(const float4*)&W[(size_t)(k0 + r) * 64 + c];
#pragma unroll
    for (int jj = 0; jj < 4; ++jj) Ws[c + jj][r] = uv.f[jj] * scale;
  }
  __syncthreads();
#pragma unroll
  for (int q = 0; q < 2; ++q) {
    int g_ = t + 256 * q;
    int d  = g_ >> 3;
    int ko = (g_ & 7) * 8;
    union { unsigned short u[8]; u32x4 v; } pk;
#pragma unroll
    for (int jj = 0; jj < 8; ++jj) pk.u[jj] = f2bf(Ws[d][ko + jj]);
    *(u32x4*)&Wt[((size_t)mtx * 64 + d) * C_DIM + k0 + ko] = pk.v;
  }
}

// ---------------------------------------------------------------------------
// qkv_proj_mfma: round-5 version (verified ~22 us). Unchanged.
// ---------------------------------------------------------------------------
__global__ __launch_bounds__(256) void qkv_proj_mfma(
    const float* __restrict__ x,
    const unsigned short* __restrict__ Wt,
    const float* __restrict__ bq, const float* __restrict__ bk, const float* __restrict__ bv,
    unsigned short* __restrict__ Qb, unsigned short* __restrict__ Kb,
    unsigned short* __restrict__ VTb)
{
  __shared__ __align__(16) short Xs[64 * 64];
  __shared__ __align__(16) short Ws[3 * 64 * 64];
  __shared__ __align__(16) unsigned short VTs[64 * 72];

  const int tid = threadIdx.x;
  const int wv = tid >> 6, lane = tid & 63, g = lane >> 4, ln15 = lane & 15;
  const size_t m0 = (size_t)blockIdx.x * 64;

  f32x4 acc[4][3];
#pragma unroll
  for (int mt = 0; mt < 4; ++mt)
#pragma unroll
    for (int j = 0; j < 3; ++j) acc[mt][j] = (f32x4){0.f, 0.f, 0.f, 0.f};

  for (int kt = 0; kt < 16; ++kt) {
    __syncthreads();
#pragma unroll
    for (int q = 0; q < 4; ++q) {
      int g_ = tid + 256 * q;
      int r = g_ >> 4, c4 = (g_ & 15) * 4;
      union { float4 f4; float f[4]; } uv;
      uv.f4 = *(const float4*)&x[(m0 + r) * C_DIM + kt * 64 + c4];
      union { unsigned short u[4]; unsigned long long ll; } pk;
#pragma unroll
      for (int jj = 0; jj < 4; ++jj) pk.u[jj] = f2bf(uv.f[jj]);
      *(unsigned long long*)((char*)Xs + r * 128 + ((c4 * 2) ^ ((r & 7) << 4))) = pk.ll;
    }
#pragma unroll
    for (int mt = 0; mt < 3; ++mt)
#pragma unroll
      for (int q = 0; q < 2; ++q) {
        int g_ = tid + 256 * q;
        int d = g_ >> 3, ko = (g_ & 7) * 8;
        u32x4 v = *(const u32x4*)&Wt[((size_t)mt * 64 + d) * C_DIM + kt * 64 + ko];
        *(u32x4*)((char*)Ws + mt * 8192 + d * 128 + ((ko * 2) ^ ((d & 7) << 4))) = v;
      }
    __syncthreads();
#pragma unroll
    for (int kc = 0; kc < 2; ++kc) {
      bf16x8 a[4];
#pragma unroll
      for (int mt = 0; mt < 4; ++mt) {
        int xr = mt * 16 + ln15;
        a[mt] = *(const bf16x8*)((const char*)Xs + xr * 128 + ((kc * 64 + g * 16) ^ ((xr & 7) << 4)));
      }
#pragma unroll
      for (int j = 0; j < 3; ++j) {
        int ntg = wv * 3 + j;
        int mtx = ntg >> 2, nc = (ntg & 3) * 16;
        int wrow = nc + ln15;
        bf16x8 bb = *(const bf16x8*)((const char*)Ws + mtx * 8192 + wrow * 128 + ((kc * 64 + g * 16) ^ ((wrow & 7) << 4)));
#pragma unroll
        for (int mt = 0; mt < 4; ++mt)
          acc[mt][j] = mfma16(a[mt], bb, acc[mt][j]);
      }
    }
  }

  __syncthreads();
#pragma unroll
  for (int j = 0; j < 3; ++j) {
    int ntg = wv * 3 + j;
    int mtx = ntg >> 2, nc = (ntg & 3) * 16;
    if (mtx < 2) {
      const float* bias = (mtx == 0) ? bq : bk;
      unsigned short* Out = (mtx == 0) ? Qb : Kb;
      float bvv = bias[nc + ln15] * ((mtx == 0) ? 0.125f : 1.0f);
#pragma unroll
      for (int mt = 0; mt < 4; ++mt)
#pragma unroll
        for (int i = 0; i < 4; ++i)
          Out[(m0 + mt * 16 + 4 * g + i) * 64 + nc + ln15] = f2bf(acc[mt][j][i] + bvv);
    } else {
      float bvv = bv[nc + ln15];
#pragma unroll
      for (int mt = 0; mt < 4; ++mt)
#pragma unroll
        for (int i = 0; i < 4; ++i)
          VTs[(nc + ln15) * 72 + mt * 16 + 4 * g + i] = f2bf(acc[mt][j][i] + bvv);
    }
  }
  __syncthreads();
  {
    int d = tid >> 2, t8 = (tid & 3) * 16;
    u32x4 v0 = *(const u32x4*)&VTs[d * 72 + t8];
    u32x4 v1 = *(const u32x4*)&VTs[d * 72 + t8 + 8];
    size_t b = m0 >> 11, tloc = m0 & 2047;
    *(u32x4*)&VTb[(b * 64 + d) * T_DIM + tloc + t8] = v0;
    *(u32x4*)&VTb[(b * 64 + d) * T_DIM + tloc + t8 + 8] = v1;
  }
}

// ---------------------------------------------------------------------------
// attn_flash: barrier-free flash attention, 32 q-rows per wave (2 m-frags).
// Block = 32-row q-tile; 4 waves split kv tiles round-robin. K/V fragment
// loads shared across both m-frags (2x MFMA per load); two independent
// softmax chains per wave give ILP. No K-prefetch (round-8 showed neutral).
// ---------------------------------------------------------------------------
__global__ __launch_bounds__(256) void attn_flash(
    const unsigned short* __restrict__ Qb,   // [B*T][64] (pre-scaled 1/8)
    const unsigned short* __restrict__ Kb,   // [B*T][64]
    const unsigned short* __restrict__ VTb,  // [B][64][T]
    float* __restrict__ out)                 // [B*T][64] f32
{
  __shared__ __align__(16) short Ps[4][2 * 16 * 64]; // per-wave, 2 m-frags
  __shared__ __align__(16) float Zs[3][2][16 * 64];  // merge slabs (waves 1..3)
  __shared__ float Ml[3][2][16][2];

  const int tid  = threadIdx.x;
  const int wv   = tid >> 6;
  const int lane = tid & 63;
  const int g    = lane >> 4;
  const int ln15 = lane & 15;

  const int qt = 63 - (blockIdx.x >> 3);    // 32-row tiles, longest first
  const int b  = blockIdx.x & 7;
  const int r0 = qt * 32;
  const int ntiles = (qt >> 1) + 1;         // 64-wide kv tiles covering r0+31

  const size_t bT = (size_t)b * T_DIM;

  bf16x8 qa[2][2];
#pragma unroll
  for (int mt = 0; mt < 2; ++mt) {
    const unsigned short* qp = Qb + (bT + r0 + mt * 16 + ln15) * 64 + g * 8;
    qa[mt][0] = *(const bf16x8*)qp;
    qa[mt][1] = *(const bf16x8*)(qp + 32);
  }

  f32x4 acc[2][4];
#pragma unroll
  for (int mt = 0; mt < 2; ++mt)
#pragma unroll
    for (int nt = 0; nt < 4; ++nt) acc[mt][nt] = (f32x4){0.f, 0.f, 0.f, 0.f};
  float m_[2][4], l_[2][4];
#pragma unroll
  for (int mt = 0; mt < 2; ++mt)
#pragma unroll
    for (int i = 0; i < 4; ++i) { m_[mt][i] = NEG_BIG; l_[mt][i] = 0.f; }

  char* myP = (char*)Ps[wv];

  for (int it = wv; it < ntiles; it += 4) {
    const int s0 = it * 64;
    // K fragments (direct from L2), shared by both m-frags
    bf16x8 kf[4][2];
#pragma unroll
    for (int nt = 0; nt < 4; ++nt) {
      const unsigned short* kp = Kb + (bT + s0 + nt * 16 + ln15) * 64 + g * 8;
      kf[nt][0] = *(const bf16x8*)kp;
      kf[nt][1] = *(const bf16x8*)(kp + 32);
    }
    // V fragments issued early (consumed after softmax)
    bf16x8 vf[4][2];
#pragma unroll
    for (int nt = 0; nt < 4; ++nt) {
      const unsigned short* vp = VTb + ((size_t)b * 64 + nt * 16 + ln15) * T_DIM + s0 + g * 8;
      vf[nt][0] = *(const bf16x8*)vp;
      vf[nt][1] = *(const bf16x8*)(vp + 32);
    }
    // QK^T: 2 m-frags x 4 n-frags
    f32x4 sfr[2][4];
#pragma unroll
    for (int mt = 0; mt < 2; ++mt)
#pragma unroll
      for (int nt = 0; nt < 4; ++nt) {
        f32x4 a = (f32x4){0.f, 0.f, 0.f, 0.f};
        a = mfma16(qa[mt][0], kf[nt][0], a);
        a = mfma16(qa[mt][1], kf[nt][1], a);
        sfr[mt][nt] = a;
      }
    // causal mask (gate on min row of the block's tile)
    if (s0 + 63 > r0) {
#pragma unroll
      for (int mt = 0; mt < 2; ++mt)
#pragma unroll
        for (int nt = 0; nt < 4; ++nt) {
          int colg = s0 + nt * 16 + ln15;
#pragma unroll
          for (int i = 0; i < 4; ++i) {
            int rowg = r0 + mt * 16 + 4 * g + i;
            if (colg > rowg) sfr[mt][nt][i] = NEG_BIG;
          }
        }
    }
    // online softmax: two independent chains (mt)
    float mx[2][4], corr[2][4];
#pragma unroll
    for (int mt = 0; mt < 2; ++mt)
#pragma unroll
      for (int i = 0; i < 4; ++i)
        mx[mt][i] = fmaxf(fmaxf(sfr[mt][0][i], sfr[mt][1][i]),
                          fmaxf(sfr[mt][2][i], sfr[mt][3][i]));
#pragma unroll
    for (int mt = 0; mt < 2; ++mt)
#pragma unroll
      for (int i = 0; i < 4; ++i) {
#pragma unroll
        for (int off = 1; off < 16; off <<= 1)
          mx[mt][i] = fmaxf(mx[mt][i], __shfl_xor(mx[mt][i], off));
        float mn = fmaxf(m_[mt][i], mx[mt][i]);
        corr[mt][i] = __expf(m_[mt][i] - mn);
        m_[mt][i] = mn;
      }
#pragma unroll
    for (int mt = 0; mt < 2; ++mt)
#pragma unroll
      for (int nt = 0; nt < 4; ++nt)
#pragma unroll
        for (int i = 0; i < 4; ++i)
          sfr[mt][nt][i] = __expf(sfr[mt][nt][i] - m_[mt][i]);
#pragma unroll
    for (int mt = 0; mt < 2; ++mt)
#pragma unroll
      for (int i = 0; i < 4; ++i) {
        float ps = sfr[mt][0][i] + sfr[mt][1][i] + sfr[mt][2][i] + sfr[mt][3][i];
#pragma unroll
        for (int off = 1; off < 16; off <<= 1)
          ps += __shfl_xor(ps, off);
        l_[mt][i] = l_[mt][i] * corr[mt][i] + ps;
      }
#pragma unroll
    for (int mt = 0; mt < 2; ++mt)
#pragma unroll
      for (int nt = 0; nt < 4; ++nt)
#pragma unroll
        for (int i = 0; i < 4; ++i)
          acc[mt][nt][i] *= corr[mt][i];
    // P -> wave-private LDS (swizzled, per m-frag slab) -> A-fragments
#pragma unroll
    for (int mt = 0; mt < 2; ++mt)
#pragma unroll
      for (int nt = 0; nt < 4; ++nt)
#pragma unroll
        for (int i = 0; i < 4; ++i) {
          int r_ = 4 * g + i;
          *(unsigned short*)(myP + mt * 2048 + r_ * 128 +
                             ((((nt * 16 + ln15)) * 2) ^ ((r_ & 7) << 4))) = f2bf(sfr[mt][nt][i]);
        }
    bf16x8 pa[2][2];
#pragma unroll
    for (int mt = 0; mt < 2; ++mt)
#pragma unroll
      for (int kc = 0; kc < 2; ++kc)
        pa[mt][kc] = *(const bf16x8*)(myP + mt * 2048 + ln15 * 128 +
                                      ((kc * 64 + g * 16) ^ ((ln15 & 7) << 4)));
    // PV: 2 x 4 x 2 = 16 MFMA
#pragma unroll
    for (int mt = 0; mt < 2; ++mt)
#pragma unroll
      for (int nt = 0; nt < 4; ++nt) {
        acc[mt][nt] = mfma16(pa[mt][0], vf[nt][0], acc[mt][nt]);
        acc[mt][nt] = mfma16(pa[mt][1], vf[nt][1], acc[mt][nt]);
      }
  }

  // 4-way merge (single barrier)
  if (wv > 0) {
#pragma unroll
    for (int mt = 0; mt < 2; ++mt) {
#pragma unroll
      for (int nt = 0; nt < 4; ++nt)
#pragma unroll
        for (int i = 0; i < 4; ++i)
          Zs[wv - 1][mt][(4 * g + i) * 64 + nt * 16 + ln15] = acc[mt][nt][i];
      if (ln15 == 0) {
#pragma unroll
        for (int i = 0; i < 4; ++i) {
          Ml[wv - 1][mt][4 * g + i][0] = m_[mt][i];
          Ml[wv - 1][mt][4 * g + i][1] = l_[mt][i];
        }
      }
    }
  }
  __syncthreads();
  if (wv == 0) {
#pragma unroll
    for (int mt = 0; mt < 2; ++mt) {
      float mm[4], e0[4], ew[3][4], inv[4];
#pragma unroll
      for (int i = 0; i < 4; ++i) {
        mm[i] = m_[mt][i];
#pragma unroll
        for (int w = 0; w < 3; ++w) mm[i] = fmaxf(mm[i], Ml[w][mt][4 * g + i][0]);
        e0[i] = __expf(m_[mt][i] - mm[i]);
        float lsum = l_[mt][i] * e0[i];
#pragma unroll
        for (int w = 0; w < 3; ++w) {
          ew[w][i] = __expf(Ml[w][mt][4 * g + i][0] - mm[i]);
          lsum += Ml[w][mt][4 * g + i][1] * ew[w][i];
        }
        inv[i] = 1.0f / lsum;
      }
      float* ob = out + (bT + r0 + mt * 16) * 64;
#pragma unroll
      for (int nt = 0; nt < 4; ++nt)
#pragma unroll
        for (int i = 0; i < 4; ++i) {
          float z = acc[mt][nt][i] * e0[i];
#pragma unroll
          for (int w = 0; w < 3; ++w)
            z += Zs[w][mt][(4 * g + i) * 64 + nt * 16 + ln15] * ew[w][i];
          ob[(size_t)(4 * g + i) * 64 + nt * 16 + ln15] = z * inv[i];
        }
    }
  }
}

// ---------------------------------------------------------------------------
extern "C" void kernel_launch(void* const* d_in, const int* in_sizes, int n_in,
                              void* d_out, int out_size, void* d_ws, size_t ws_size,
                              hipStream_t stream)
{
  const float* x  = (const float*)d_in[0];
  const float* Wq = (const float*)d_in[1];
  const float* bq = (const float*)d_in[2];
  const float* Wk = (const float*)d_in[3];
  const float* bk = (const float*)d_in[4];
  const float* Wv = (const float*)d_in[5];
  const float* bv = (const float*)d_in[6];
  float* out = (float*)d_out;

  char* ws = (char*)d_ws;
  unsigned short* Wt  = (unsigned short*)(ws);                      // 384 KB
  unsigned short* Qb  = (unsigned short*)(ws + (1u << 19));         // 2 MB
  unsigned short* Kb  = (unsigned short*)(ws + (1u << 19) + (1u << 21));
  unsigned short* VTb = (unsigned short*)(ws + (1u << 19) + (2u << 21));

  prep_w<<<48, 256, 0, stream>>>(Wq, Wk, Wv, Wt);
  qkv_proj_mfma<<<256, 256, 0, stream>>>(x, Wt, bq, bk, bv, Qb, Kb, VTb);
  attn_flash<<<512, 256, 0, stream>>>(Qb, Kb, VTb, out);
}

// Round 10
// 57.612 us; speedup vs baseline: 1.1945x; 1.0664x over previous
//
#include <hip/hip_runtime.h>
#include <hip/hip_bf16.h>
#include <cstdint>
#include <cstddef>

typedef __attribute__((ext_vector_type(8))) short bf16x8;
typedef __attribute__((ext_vector_type(4))) float f32x4;
typedef __attribute__((ext_vector_type(4))) unsigned int u32x4;

#define T_DIM 2048
#define C_DIM 1024
#define B_DIM 8
#define NEG_BIG (-3.0e38f)

__device__ __forceinline__ unsigned short f2bf(float f) {
  union { __hip_bfloat16 h; unsigned short u; } cv;
  cv.h = __float2bfloat16(f);
  return cv.u;
}
__device__ __forceinline__ f32x4 mfma16(bf16x8 a, bf16x8 b, f32x4 c) {
  return __builtin_amdgcn_mfma_f32_16x16x32_bf16(a, b, c, 0, 0, 0);
}

// ---------------------------------------------------------------------------
// prep_w: W [1024][64] f32 -> Wt [3][64][1024] bf16 (transposed; Wq scaled 1/8)
// (unchanged)
// ---------------------------------------------------------------------------
__global__ __launch_bounds__(256) void prep_w(
    const float* __restrict__ Wq, const float* __restrict__ Wk,
    const float* __restrict__ Wv, unsigned short* __restrict__ Wt)
{
  const int mtx = blockIdx.x >> 4;
  const int k0  = (blockIdx.x & 15) * 64;
  const float* W = (mtx == 0) ? Wq : ((mtx == 1) ? Wk : Wv);
  const float scale = (mtx == 0) ? 0.125f : 1.0f;
  __shared__ float Ws[64][65];
  const int t = threadIdx.x;
#pragma unroll
  for (int j = 0; j < 4; ++j) {
    int r = (t >> 4) + 16 * j;
    int c = (t & 15) * 4;
    union { float4 f4; float f[4]; } uv;
    uv.f4 = *(const float4*)&W[(size_t)(k0 + r) * 64 + c];
#pragma unroll
    for (int jj = 0; jj < 4; ++jj) Ws[c + jj][r] = uv.f[jj] * scale;
  }
  __syncthreads();
#pragma unroll
  for (int q = 0; q < 2; ++q) {
    int g_ = t + 256 * q;
    int d  = g_ >> 3;
    int ko = (g_ & 7) * 8;
    union { unsigned short u[8]; u32x4 v; } pk;
#pragma unroll
    for (int jj = 0; jj < 8; ++jj) pk.u[jj] = f2bf(Ws[d][ko + jj]);
    *(u32x4*)&Wt[((size_t)mtx * 64 + d) * C_DIM + k0 + ko] = pk.v;
  }
}

// ---------------------------------------------------------------------------
// qkv_proj_mfma: 64 rows/block, 256 blocks (round-5 work decomposition, no
// redundant loads) + single-barrier double-buffered pipeline:
//   X reg-staged 2-deep (xA/xB named, ~1200cyc cover vs ~900cyc HBM),
//   W reg-staged 1-deep (L2 ~250cyc, covered by compute),
//   one __syncthreads per kt, next loads in flight across the barrier.
// ---------------------------------------------------------------------------
__global__ __launch_bounds__(256) void qkv_proj_mfma(
    const float* __restrict__ x,
    const unsigned short* __restrict__ Wt,
    const float* __restrict__ bq, const float* __restrict__ bk, const float* __restrict__ bv,
    unsigned short* __restrict__ Qb, unsigned short* __restrict__ Kb,
    unsigned short* __restrict__ VTb)
{
  __shared__ __align__(16) short Xs[2][64 * 64];       // 8 KB each
  __shared__ __align__(16) short Wsb[2][3 * 64 * 64];  // 24 KB each
  __shared__ __align__(16) unsigned short VTs[64 * 72];

  const int tid = threadIdx.x;
  const int wv = tid >> 6, lane = tid & 63, g = lane >> 4, ln15 = lane & 15;
  const size_t m0 = (size_t)blockIdx.x * 64;

  f32x4 acc[4][3];
#pragma unroll
  for (int mt = 0; mt < 4; ++mt)
#pragma unroll
    for (int j = 0; j < 3; ++j) acc[mt][j] = (f32x4){0.f, 0.f, 0.f, 0.f};

  float4 xA[4], xB[4];
  u32x4 wr[6];

  auto issueX = [&](float4 (&xr)[4], int kt) {
    if (kt >= 16) return;
#pragma unroll
    for (int q = 0; q < 4; ++q) {
      int g_ = tid + 256 * q;
      int r = g_ >> 4, c4 = (g_ & 15) * 4;
      xr[q] = *(const float4*)&x[(m0 + r) * C_DIM + kt * 64 + c4];
    }
  };
  auto issueW = [&](int kt) {
    if (kt >= 16) return;
#pragma unroll
    for (int mt = 0; mt < 3; ++mt)
#pragma unroll
      for (int q = 0; q < 2; ++q) {
        int g_ = tid + 256 * q;
        int d = g_ >> 3, ko = (g_ & 7) * 8;
        wr[mt * 2 + q] = *(const u32x4*)&Wt[((size_t)mt * 64 + d) * C_DIM + kt * 64 + ko];
      }
  };
  auto writeXb = [&](int nb, const float4 (&xr)[4]) {
#pragma unroll
    for (int q = 0; q < 4; ++q) {
      int g_ = tid + 256 * q;
      int r = g_ >> 4, c4 = (g_ & 15) * 4;
      const float* f = (const float*)&xr[q];
      union { unsigned short u[4]; unsigned long long ll; } pk;
#pragma unroll
      for (int jj = 0; jj < 4; ++jj) pk.u[jj] = f2bf(f[jj]);
      *(unsigned long long*)((char*)Xs[nb] + r * 128 + ((c4 * 2) ^ ((r & 7) << 4))) = pk.ll;
    }
  };
  auto writeWb = [&](int nb) {
#pragma unroll
    for (int mt = 0; mt < 3; ++mt)
#pragma unroll
      for (int q = 0; q < 2; ++q) {
        int g_ = tid + 256 * q;
        int d = g_ >> 3, ko = (g_ & 7) * 8;
        *(u32x4*)((char*)Wsb[nb] + mt * 8192 + d * 128 + ((ko * 2) ^ ((d & 7) << 4))) = wr[mt * 2 + q];
      }
  };
  auto compute = [&](int nb) {
#pragma unroll
    for (int kc = 0; kc < 2; ++kc) {
      bf16x8 a[4];
#pragma unroll
      for (int mt = 0; mt < 4; ++mt) {
        int xr = mt * 16 + ln15;
        a[mt] = *(const bf16x8*)((const char*)Xs[nb] + xr * 128 + ((kc * 64 + g * 16) ^ ((xr & 7) << 4)));
      }
#pragma unroll
      for (int j = 0; j < 3; ++j) {
        int ntg = wv * 3 + j;
        int mtx = ntg >> 2, nc = (ntg & 3) * 16;
        int wrow = nc + ln15;
        bf16x8 bb = *(const bf16x8*)((const char*)Wsb[nb] + mtx * 8192 + wrow * 128 + ((kc * 64 + g * 16) ^ ((wrow & 7) << 4)));
#pragma unroll
        for (int mt = 0; mt < 4; ++mt)
          acc[mt][j] = mfma16(a[mt], bb, acc[mt][j]);
      }
    }
  };

  // prologue: fill buf0 (one exposed load), issue kt=1 X early
  issueX(xA, 0); issueW(0);
  writeXb(0, xA); writeWb(0);
  issueX(xB, 1);
  __syncthreads();

  for (int kt = 0; kt < 16; kt += 2) {
    // buf0 holds kt; xB has kt+1 in flight
    issueW(kt + 1);
    issueX(xA, kt + 2);
    compute(0);
    if (kt + 1 < 16) { writeXb(1, xB); writeWb(1); }
    __syncthreads();
    if (kt + 1 < 16) {
      issueW(kt + 2);
      issueX(xB, kt + 3);
      compute(1);
      if (kt + 2 < 16) { writeXb(0, xA); writeWb(0); }
      __syncthreads();
    }
  }

  // epilogue: Q/K direct; V -> LDS transpose tile -> coalesced VTb (unchanged)
#pragma unroll
  for (int j = 0; j < 3; ++j) {
    int ntg = wv * 3 + j;
    int mtx = ntg >> 2, nc = (ntg & 3) * 16;
    if (mtx < 2) {
      const float* bias = (mtx == 0) ? bq : bk;
      unsigned short* Out = (mtx == 0) ? Qb : Kb;
      float bvv = bias[nc + ln15] * ((mtx == 0) ? 0.125f : 1.0f);
#pragma unroll
      for (int mt = 0; mt < 4; ++mt)
#pragma unroll
        for (int i = 0; i < 4; ++i)
          Out[(m0 + mt * 16 + 4 * g + i) * 64 + nc + ln15] = f2bf(acc[mt][j][i] + bvv);
    } else {
      float bvv = bv[nc + ln15];
#pragma unroll
      for (int mt = 0; mt < 4; ++mt)
#pragma unroll
        for (int i = 0; i < 4; ++i)
          VTs[(nc + ln15) * 72 + mt * 16 + 4 * g + i] = f2bf(acc[mt][j][i] + bvv);
    }
  }
  __syncthreads();
  {
    int d = tid >> 2, t8 = (tid & 3) * 16;
    u32x4 v0 = *(const u32x4*)&VTs[d * 72 + t8];
    u32x4 v1 = *(const u32x4*)&VTs[d * 72 + t8 + 8];
    size_t b = m0 >> 11, tloc = m0 & 2047;
    *(u32x4*)&VTb[(b * 64 + d) * T_DIM + tloc + t8] = v0;
    *(u32x4*)&VTb[(b * 64 + d) * T_DIM + tloc + t8 + 8] = v1;
  }
}

// ---------------------------------------------------------------------------
// attn_flash: round-9 version, UNCHANGED (32 q-rows/wave, barrier-free,
// split-k x4, ~33 us).
// ---------------------------------------------------------------------------
__global__ __launch_bounds__(256) void attn_flash(
    const unsigned short* __restrict__ Qb,   // [B*T][64] (pre-scaled 1/8)
    const unsigned short* __restrict__ Kb,   // [B*T][64]
    const unsigned short* __restrict__ VTb,  // [B][64][T]
    float* __restrict__ out)                 // [B*T][64] f32
{
  __shared__ __align__(16) short Ps[4][2 * 16 * 64];
  __shared__ __align__(16) float Zs[3][2][16 * 64];
  __shared__ float Ml[3][2][16][2];

  const int tid  = threadIdx.x;
  const int wv   = tid >> 6;
  const int lane = tid & 63;
  const int g    = lane >> 4;
  const int ln15 = lane & 15;

  const int qt = 63 - (blockIdx.x >> 3);
  const int b  = blockIdx.x & 7;
  const int r0 = qt * 32;
  const int ntiles = (qt >> 1) + 1;

  const size_t bT = (size_t)b * T_DIM;

  bf16x8 qa[2][2];
#pragma unroll
  for (int mt = 0; mt < 2; ++mt) {
    const unsigned short* qp = Qb + (bT + r0 + mt * 16 + ln15) * 64 + g * 8;
    qa[mt][0] = *(const bf16x8*)qp;
    qa[mt][1] = *(const bf16x8*)(qp + 32);
  }

  f32x4 acc[2][4];
#pragma unroll
  for (int mt = 0; mt < 2; ++mt)
#pragma unroll
    for (int nt = 0; nt < 4; ++nt) acc[mt][nt] = (f32x4){0.f, 0.f, 0.f, 0.f};
  float m_[2][4], l_[2][4];
#pragma unroll
  for (int mt = 0; mt < 2; ++mt)
#pragma unroll
    for (int i = 0; i < 4; ++i) { m_[mt][i] = NEG_BIG; l_[mt][i] = 0.f; }

  char* myP = (char*)Ps[wv];

  for (int it = wv; it < ntiles; it += 4) {
    const int s0 = it * 64;
    bf16x8 kf[4][2];
#pragma unroll
    for (int nt = 0; nt < 4; ++nt) {
      const unsigned short* kp = Kb + (bT + s0 + nt * 16 + ln15) * 64 + g * 8;
      kf[nt][0] = *(const bf16x8*)kp;
      kf[nt][1] = *(const bf16x8*)(kp + 32);
    }
    bf16x8 vf[4][2];
#pragma unroll
    for (int nt = 0; nt < 4; ++nt) {
      const unsigned short* vp = VTb + ((size_t)b * 64 + nt * 16 + ln15) * T_DIM + s0 + g * 8;
      vf[nt][0] = *(const bf16x8*)vp;
      vf[nt][1] = *(const bf16x8*)(vp + 32);
    }
    f32x4 sfr[2][4];
#pragma unroll
    for (int mt = 0; mt < 2; ++mt)
#pragma unroll
      for (int nt = 0; nt < 4; ++nt) {
        f32x4 a = (f32x4){0.f, 0.f, 0.f, 0.f};
        a = mfma16(qa[mt][0], kf[nt][0], a);
        a = mfma16(qa[mt][1], kf[nt][1], a);
        sfr[mt][nt] = a;
      }
    if (s0 + 63 > r0) {
#pragma unroll
      for (int mt = 0; mt < 2; ++mt)
#pragma unroll
        for (int nt = 0; nt < 4; ++nt) {
          int colg = s0 + nt * 16 + ln15;
#pragma unroll
          for (int i = 0; i < 4; ++i) {
            int rowg = r0 + mt * 16 + 4 * g + i;
            if (colg > rowg) sfr[mt][nt][i] = NEG_BIG;
          }
        }
    }
    float mx[2][4], corr[2][4];
#pragma unroll
    for (int mt = 0; mt < 2; ++mt)
#pragma unroll
      for (int i = 0; i < 4; ++i)
        mx[mt][i] = fmaxf(fmaxf(sfr[mt][0][i], sfr[mt][1][i]),
                          fmaxf(sfr[mt][2][i], sfr[mt][3][i]));
#pragma unroll
    for (int mt = 0; mt < 2; ++mt)
#pragma unroll
      for (int i = 0; i < 4; ++i) {
#pragma unroll
        for (int off = 1; off < 16; off <<= 1)
          mx[mt][i] = fmaxf(mx[mt][i], __shfl_xor(mx[mt][i], off));
        float mn = fmaxf(m_[mt][i], mx[mt][i]);
        corr[mt][i] = __expf(m_[mt][i] - mn);
        m_[mt][i] = mn;
      }
#pragma unroll
    for (int mt = 0; mt < 2; ++mt)
#pragma unroll
      for (int nt = 0; nt < 4; ++nt)
#pragma unroll
        for (int i = 0; i < 4; ++i)
          sfr[mt][nt][i] = __expf(sfr[mt][nt][i] - m_[mt][i]);
#pragma unroll
    for (int mt = 0; mt < 2; ++mt)
#pragma unroll
      for (int i = 0; i < 4; ++i) {
        float ps = sfr[mt][0][i] + sfr[mt][1][i] + sfr[mt][2][i] + sfr[mt][3][i];
#pragma unroll
        for (int off = 1; off < 16; off <<= 1)
          ps += __shfl_xor(ps, off);
        l_[mt][i] = l_[mt][i] * corr[mt][i] + ps;
      }
#pragma unroll
    for (int mt = 0; mt < 2; ++mt)
#pragma unroll
      for (int nt = 0; nt < 4; ++nt)
#pragma unroll
        for (int i = 0; i < 4; ++i)
          acc[mt][nt][i] *= corr[mt][i];
#pragma unroll
    for (int mt = 0; mt < 2; ++mt)
#pragma unroll
      for (int nt = 0; nt < 4; ++nt)
#pragma unroll
        for (int i = 0; i < 4; ++i) {
          int r_ = 4 * g + i;
          *(unsigned short*)(myP + mt * 2048 + r_ * 128 +
                             ((((nt * 16 + ln15)) * 2) ^ ((r_ & 7) << 4))) = f2bf(sfr[mt][nt][i]);
        }
    bf16x8 pa[2][2];
#pragma unroll
    for (int mt = 0; mt < 2; ++mt)
#pragma unroll
      for (int kc = 0; kc < 2; ++kc)
        pa[mt][kc] = *(const bf16x8*)(myP + mt * 2048 + ln15 * 128 +
                                      ((kc * 64 + g * 16) ^ ((ln15 & 7) << 4)));
#pragma unroll
    for (int mt = 0; mt < 2; ++mt)
#pragma unroll
      for (int nt = 0; nt < 4; ++nt) {
        acc[mt][nt] = mfma16(pa[mt][0], vf[nt][0], acc[mt][nt]);
        acc[mt][nt] = mfma16(pa[mt][1], vf[nt][1], acc[mt][nt]);
      }
  }

  if (wv > 0) {
#pragma unroll
    for (int mt = 0; mt < 2; ++mt) {
#pragma unroll
      for (int nt = 0; nt < 4; ++nt)
#pragma unroll
        for (int i = 0; i < 4; ++i)
          Zs[wv - 1][mt][(4 * g + i) * 64 + nt * 16 + ln15] = acc[mt][nt][i];
      if (ln15 == 0) {
#pragma unroll
        for (int i = 0; i < 4; ++i) {
          Ml[wv - 1][mt][4 * g + i][0] = m_[mt][i];
          Ml[wv - 1][mt][4 * g + i][1] = l_[mt][i];
        }
      }
    }
  }
  __syncthreads();
  if (wv == 0) {
#pragma unroll
    for (int mt = 0; mt < 2; ++mt) {
      float mm[4], e0[4], ew[3][4], inv[4];
#pragma unroll
      for (int i = 0; i < 4; ++i) {
        mm[i] = m_[mt][i];
#pragma unroll
        for (int w = 0; w < 3; ++w) mm[i] = fmaxf(mm[i], Ml[w][mt][4 * g + i][0]);
        e0[i] = __expf(m_[mt][i] - mm[i]);
        float lsum = l_[mt][i] * e0[i];
#pragma unroll
        for (int w = 0; w < 3; ++w) {
          ew[w][i] = __expf(Ml[w][mt][4 * g + i][0] - mm[i]);
          lsum += Ml[w][mt][4 * g + i][1] * ew[w][i];
        }
        inv[i] = 1.0f / lsum;
      }
      float* ob = out + (bT + r0 + mt * 16) * 64;
#pragma unroll
      for (int nt = 0; nt < 4; ++nt)
#pragma unroll
        for (int i = 0; i < 4; ++i) {
          float z = acc[mt][nt][i] * e0[i];
#pragma unroll
          for (int w = 0; w < 3; ++w)
            z += Zs[w][mt][(4 * g + i) * 64 + nt * 16 + ln15] * ew[w][i];
          ob[(size_t)(4 * g + i) * 64 + nt * 16 + ln15] = z * inv[i];
        }
    }
  }
}

// ---------------------------------------------------------------------------
extern "C" void kernel_launch(void* const* d_in, const int* in_sizes, int n_in,
                              void* d_out, int out_size, void* d_ws, size_t ws_size,
                              hipStream_t stream)
{
  const float* x  = (const float*)d_in[0];
  const float* Wq = (const float*)d_in[1];
  const float* bq = (const float*)d_in[2];
  const float* Wk = (const float*)d_in[3];
  const float* bk = (const float*)d_in[4];
  const float* Wv = (const float*)d_in[5];
  const float* bv = (const float*)d_in[6];
  float* out = (float*)d_out;

  char* ws = (char*)d_ws;
  unsigned short* Wt  = (unsigned short*)(ws);                      // 384 KB
  unsigned short* Qb  = (unsigned short*)(ws + (1u << 19));         // 2 MB
  unsigned short* Kb  = (unsigned short*)(ws + (1u << 19) + (1u << 21));
  unsigned short* VTb = (unsigned short*)(ws + (1u << 19) + (2u << 21));

  prep_w<<<48, 256, 0, stream>>>(Wq, Wk, Wv, Wt);
  qkv_proj_mfma<<<256, 256, 0, stream>>>(x, Wt, bq, bk, bv, Qb, Kb, VTb);
  attn_flash<<<512, 256, 0, stream>>>(Qb, Kb, VTb, out);
}

// Round 11
// 53.738 us; speedup vs baseline: 1.2806x; 1.0721x over previous
//
#include <hip/hip_runtime.h>
#include <hip/hip_bf16.h>
#include <cstdint>
#include <cstddef>

typedef __attribute__((ext_vector_type(8))) short bf16x8;
typedef __attribute__((ext_vector_type(4))) float f32x4;
typedef __attribute__((ext_vector_type(4))) unsigned int u32x4;

#define T_DIM 2048
#define C_DIM 1024
#define B_DIM 8
#define NEG_BIG (-3.0e38f)

__device__ __forceinline__ unsigned short f2bf(float f) {
  union { __hip_bfloat16 h; unsigned short u; } cv;
  cv.h = __float2bfloat16(f);
  return cv.u;
}
__device__ __forceinline__ f32x4 mfma16(bf16x8 a, bf16x8 b, f32x4 c) {
  return __builtin_amdgcn_mfma_f32_16x16x32_bf16(a, b, c, 0, 0, 0);
}

// ---------------------------------------------------------------------------
// prep_w: W [1024][64] f32 -> Wt [3][64][1024] bf16 (transposed; Wq scaled 1/8)
// (unchanged)
// ---------------------------------------------------------------------------
__global__ __launch_bounds__(256) void prep_w(
    const float* __restrict__ Wq, const float* __restrict__ Wk,
    const float* __restrict__ Wv, unsigned short* __restrict__ Wt)
{
  const int mtx = blockIdx.x >> 4;
  const int k0  = (blockIdx.x & 15) * 64;
  const float* W = (mtx == 0) ? Wq : ((mtx == 1) ? Wk : Wv);
  const float scale = (mtx == 0) ? 0.125f : 1.0f;
  __shared__ float Ws[64][65];
  const int t = threadIdx.x;
#pragma unroll
  for (int j = 0; j < 4; ++j) {
    int r = (t >> 4) + 16 * j;
    int c = (t & 15) * 4;
    union { float4 f4; float f[4]; } uv;
    uv.f4 = *(const float4*)&W[(size_t)(k0 + r) * 64 + c];
#pragma unroll
    for (int jj = 0; jj < 4; ++jj) Ws[c + jj][r] = uv.f[jj] * scale;
  }
  __syncthreads();
#pragma unroll
  for (int q = 0; q < 2; ++q) {
    int g_ = t + 256 * q;
    int d  = g_ >> 3;
    int ko = (g_ & 7) * 8;
    union { unsigned short u[8]; u32x4 v; } pk;
#pragma unroll
    for (int jj = 0; jj < 8; ++jj) pk.u[jj] = f2bf(Ws[d][ko + jj]);
    *(u32x4*)&Wt[((size_t)mtx * 64 + d) * C_DIM + k0 + ko] = pk.v;
  }
}

// ---------------------------------------------------------------------------
// qkv_proj_mfma: round-10 pipelined version (verified ~18 us). Unchanged.
// ---------------------------------------------------------------------------
__global__ __launch_bounds__(256) void qkv_proj_mfma(
    const float* __restrict__ x,
    const unsigned short* __restrict__ Wt,
    const float* __restrict__ bq, const float* __restrict__ bk, const float* __restrict__ bv,
    unsigned short* __restrict__ Qb, unsigned short* __restrict__ Kb,
    unsigned short* __restrict__ VTb)
{
  __shared__ __align__(16) short Xs[2][64 * 64];
  __shared__ __align__(16) short Wsb[2][3 * 64 * 64];
  __shared__ __align__(16) unsigned short VTs[64 * 72];

  const int tid = threadIdx.x;
  const int wv = tid >> 6, lane = tid & 63, g = lane >> 4, ln15 = lane & 15;
  const size_t m0 = (size_t)blockIdx.x * 64;

  f32x4 acc[4][3];
#pragma unroll
  for (int mt = 0; mt < 4; ++mt)
#pragma unroll
    for (int j = 0; j < 3; ++j) acc[mt][j] = (f32x4){0.f, 0.f, 0.f, 0.f};

  float4 xA[4], xB[4];
  u32x4 wr[6];

  auto issueX = [&](float4 (&xr)[4], int kt) {
    if (kt >= 16) return;
#pragma unroll
    for (int q = 0; q < 4; ++q) {
      int g_ = tid + 256 * q;
      int r = g_ >> 4, c4 = (g_ & 15) * 4;
      xr[q] = *(const float4*)&x[(m0 + r) * C_DIM + kt * 64 + c4];
    }
  };
  auto issueW = [&](int kt) {
    if (kt >= 16) return;
#pragma unroll
    for (int mt = 0; mt < 3; ++mt)
#pragma unroll
      for (int q = 0; q < 2; ++q) {
        int g_ = tid + 256 * q;
        int d = g_ >> 3, ko = (g_ & 7) * 8;
        wr[mt * 2 + q] = *(const u32x4*)&Wt[((size_t)mt * 64 + d) * C_DIM + kt * 64 + ko];
      }
  };
  auto writeXb = [&](int nb, const float4 (&xr)[4]) {
#pragma unroll
    for (int q = 0; q < 4; ++q) {
      int g_ = tid + 256 * q;
      int r = g_ >> 4, c4 = (g_ & 15) * 4;
      const float* f = (const float*)&xr[q];
      union { unsigned short u[4]; unsigned long long ll; } pk;
#pragma unroll
      for (int jj = 0; jj < 4; ++jj) pk.u[jj] = f2bf(f[jj]);
      *(unsigned long long*)((char*)Xs[nb] + r * 128 + ((c4 * 2) ^ ((r & 7) << 4))) = pk.ll;
    }
  };
  auto writeWb = [&](int nb) {
#pragma unroll
    for (int mt = 0; mt < 3; ++mt)
#pragma unroll
      for (int q = 0; q < 2; ++q) {
        int g_ = tid + 256 * q;
        int d = g_ >> 3, ko = (g_ & 7) * 8;
        *(u32x4*)((char*)Wsb[nb] + mt * 8192 + d * 128 + ((ko * 2) ^ ((d & 7) << 4))) = wr[mt * 2 + q];
      }
  };
  auto compute = [&](int nb) {
#pragma unroll
    for (int kc = 0; kc < 2; ++kc) {
      bf16x8 a[4];
#pragma unroll
      for (int mt = 0; mt < 4; ++mt) {
        int xr = mt * 16 + ln15;
        a[mt] = *(const bf16x8*)((const char*)Xs[nb] + xr * 128 + ((kc * 64 + g * 16) ^ ((xr & 7) << 4)));
      }
#pragma unroll
      for (int j = 0; j < 3; ++j) {
        int ntg = wv * 3 + j;
        int mtx = ntg >> 2, nc = (ntg & 3) * 16;
        int wrow = nc + ln15;
        bf16x8 bb = *(const bf16x8*)((const char*)Wsb[nb] + mtx * 8192 + wrow * 128 + ((kc * 64 + g * 16) ^ ((wrow & 7) << 4)));
#pragma unroll
        for (int mt = 0; mt < 4; ++mt)
          acc[mt][j] = mfma16(a[mt], bb, acc[mt][j]);
      }
    }
  };

  issueX(xA, 0); issueW(0);
  writeXb(0, xA); writeWb(0);
  issueX(xB, 1);
  __syncthreads();

  for (int kt = 0; kt < 16; kt += 2) {
    issueW(kt + 1);
    issueX(xA, kt + 2);
    compute(0);
    if (kt + 1 < 16) { writeXb(1, xB); writeWb(1); }
    __syncthreads();
    if (kt + 1 < 16) {
      issueW(kt + 2);
      issueX(xB, kt + 3);
      compute(1);
      if (kt + 2 < 16) { writeXb(0, xA); writeWb(0); }
      __syncthreads();
    }
  }

#pragma unroll
  for (int j = 0; j < 3; ++j) {
    int ntg = wv * 3 + j;
    int mtx = ntg >> 2, nc = (ntg & 3) * 16;
    if (mtx < 2) {
      const float* bias = (mtx == 0) ? bq : bk;
      unsigned short* Out = (mtx == 0) ? Qb : Kb;
      float bvv = bias[nc + ln15] * ((mtx == 0) ? 0.125f : 1.0f);
#pragma unroll
      for (int mt = 0; mt < 4; ++mt)
#pragma unroll
        for (int i = 0; i < 4; ++i)
          Out[(m0 + mt * 16 + 4 * g + i) * 64 + nc + ln15] = f2bf(acc[mt][j][i] + bvv);
    } else {
      float bvv = bv[nc + ln15];
#pragma unroll
      for (int mt = 0; mt < 4; ++mt)
#pragma unroll
        for (int i = 0; i < 4; ++i)
          VTs[(nc + ln15) * 72 + mt * 16 + 4 * g + i] = f2bf(acc[mt][j][i] + bvv);
    }
  }
  __syncthreads();
  {
    int d = tid >> 2, t8 = (tid & 3) * 16;
    u32x4 v0 = *(const u32x4*)&VTs[d * 72 + t8];
    u32x4 v1 = *(const u32x4*)&VTs[d * 72 + t8 + 8];
    size_t b = m0 >> 11, tloc = m0 & 2047;
    *(u32x4*)&VTb[(b * 64 + d) * T_DIM + tloc + t8] = v0;
    *(u32x4*)&VTb[(b * 64 + d) * T_DIM + tloc + t8 + 8] = v1;
  }
}

// ---------------------------------------------------------------------------
// attn_flash: SWAPPED-OPERAND flash attention. S^T = mfma(K,Q) so each lane
// owns one q-column (q = r0+mt*16+ln15): softmax m/l are per-lane SCALARS
// (2 shfl per reduce vs 4-deep chains), P^T packs to 8 ds_write_b64 (vs 32
// b16), PV = mfma(V^T, P^T) -> Z^T. Same global loads as round 9 (A/B frag
// lane maps identical). Merge/epilogue rewritten for transposed acc.
// ---------------------------------------------------------------------------
__global__ __launch_bounds__(256) void attn_flash(
    const unsigned short* __restrict__ Qb,   // [B*T][64] (pre-scaled 1/8)
    const unsigned short* __restrict__ Kb,   // [B*T][64]
    const unsigned short* __restrict__ VTb,  // [B][64][T]
    float* __restrict__ out)                 // [B*T][64] f32
{
  __shared__ __align__(16) short Ps[4][2 * 16 * 64]; // per-wave P^T as [q][kv]
  __shared__ __align__(16) float Zs[3][2][16 * 68];  // [q][d] padded stride 68
  __shared__ float Ml[3][2][16][2];

  const int tid  = threadIdx.x;
  const int wv   = tid >> 6;
  const int lane = tid & 63;
  const int g    = lane >> 4;
  const int ln15 = lane & 15;

  const int qt = 63 - (blockIdx.x >> 3);    // 32-row q-tiles, longest first
  const int b  = blockIdx.x & 7;
  const int r0 = qt * 32;
  const int ntiles = (qt >> 1) + 1;

  const size_t bT = (size_t)b * T_DIM;

  bf16x8 qa[2][2];                          // B-operand: Q[q=ln15][d=g*8+j]
#pragma unroll
  for (int mt = 0; mt < 2; ++mt) {
    const unsigned short* qp = Qb + (bT + r0 + mt * 16 + ln15) * 64 + g * 8;
    qa[mt][0] = *(const bf16x8*)qp;
    qa[mt][1] = *(const bf16x8*)(qp + 32);
  }

  f32x4 acc[2][4];                          // Z^T: [mt][dt], row d=4g+i, col q=ln15
#pragma unroll
  for (int mt = 0; mt < 2; ++mt)
#pragma unroll
    for (int dt = 0; dt < 4; ++dt) acc[mt][dt] = (f32x4){0.f, 0.f, 0.f, 0.f};
  float m_[2], l_[2];
#pragma unroll
  for (int mt = 0; mt < 2; ++mt) { m_[mt] = NEG_BIG; l_[mt] = 0.f; }

  char* myP = (char*)Ps[wv];

  for (int it = wv; it < ntiles; it += 4) {
    const int s0 = it * 64;
    // K fragments: A-operand rows kv=nt*16+ln15, k=d (same loads as r9)
    bf16x8 kf[4][2];
#pragma unroll
    for (int nt = 0; nt < 4; ++nt) {
      const unsigned short* kp = Kb + (bT + s0 + nt * 16 + ln15) * 64 + g * 8;
      kf[nt][0] = *(const bf16x8*)kp;
      kf[nt][1] = *(const bf16x8*)(kp + 32);
    }
    // V^T fragments: A-operand rows d=dt*16+ln15, k=kv (same loads as r9)
    bf16x8 vf[4][2];
#pragma unroll
    for (int dt = 0; dt < 4; ++dt) {
      const unsigned short* vp = VTb + ((size_t)b * 64 + dt * 16 + ln15) * T_DIM + s0 + g * 8;
      vf[dt][0] = *(const bf16x8*)vp;
      vf[dt][1] = *(const bf16x8*)(vp + 32);
    }
    // S^T = K·Q^T: st[mt][nt] rows kv=4g+i (local), col q=ln15
    f32x4 st[2][4];
#pragma unroll
    for (int mt = 0; mt < 2; ++mt)
#pragma unroll
      for (int nt = 0; nt < 4; ++nt) {
        f32x4 a = (f32x4){0.f, 0.f, 0.f, 0.f};
        a = mfma16(kf[nt][0], qa[mt][0], a);
        a = mfma16(kf[nt][1], qa[mt][1], a);
        st[mt][nt] = a;
      }
    // causal mask: kv = s0+nt*16+4g+i vs q = r0+mt*16+ln15
    if (s0 + 63 > r0) {
#pragma unroll
      for (int mt = 0; mt < 2; ++mt) {
        const int qg = r0 + mt * 16 + ln15;
#pragma unroll
        for (int nt = 0; nt < 4; ++nt) {
          const int kvb = s0 + nt * 16 + 4 * g;
#pragma unroll
          for (int i = 0; i < 4; ++i)
            if (kvb + i > qg) st[mt][nt][i] = NEG_BIG;
        }
      }
    }
    // per-q softmax (scalar state per lane)
#pragma unroll
    for (int mt = 0; mt < 2; ++mt) {
      f32x4 t4;
#pragma unroll
      for (int i = 0; i < 4; ++i)
        t4[i] = fmaxf(fmaxf(st[mt][0][i], st[mt][1][i]), fmaxf(st[mt][2][i], st[mt][3][i]));
      float mx = fmaxf(fmaxf(t4[0], t4[1]), fmaxf(t4[2], t4[3]));
      mx = fmaxf(mx, __shfl_xor(mx, 16));
      mx = fmaxf(mx, __shfl_xor(mx, 32));
      const float mn = fmaxf(m_[mt], mx);
      const float corr = __expf(m_[mt] - mn);
      m_[mt] = mn;
#pragma unroll
      for (int nt = 0; nt < 4; ++nt)
#pragma unroll
        for (int i = 0; i < 4; ++i)
          st[mt][nt][i] = __expf(st[mt][nt][i] - mn);
      float ps = 0.f;
#pragma unroll
      for (int nt = 0; nt < 4; ++nt)
        ps += (st[mt][nt][0] + st[mt][nt][1]) + (st[mt][nt][2] + st[mt][nt][3]);
      ps += __shfl_xor(ps, 16);
      ps += __shfl_xor(ps, 32);
      l_[mt] = l_[mt] * corr + ps;
#pragma unroll
      for (int dt = 0; dt < 4; ++dt)
#pragma unroll
        for (int i = 0; i < 4; ++i)
          acc[mt][dt][i] *= corr;
      // P^T pack: 4 consecutive kv per lane -> one b64 write per nt
#pragma unroll
      for (int nt = 0; nt < 4; ++nt) {
        unsigned int lo = (unsigned int)f2bf(st[mt][nt][0]) | ((unsigned int)f2bf(st[mt][nt][1]) << 16);
        unsigned int hi = (unsigned int)f2bf(st[mt][nt][2]) | ((unsigned int)f2bf(st[mt][nt][3]) << 16);
        *(unsigned long long*)(myP + mt * 2048 + ln15 * 128 +
                               ((nt * 32 + g * 8) ^ ((ln15 & 7) << 4))) =
            ((unsigned long long)hi << 32) | lo;
      }
    }
    // P^T B-operand read (row q=ln15, 8 consecutive kv) + PV
    bf16x8 pb[2][2];
#pragma unroll
    for (int mt = 0; mt < 2; ++mt)
#pragma unroll
      for (int kc = 0; kc < 2; ++kc)
        pb[mt][kc] = *(const bf16x8*)(myP + mt * 2048 + ln15 * 128 +
                                      ((kc * 64 + g * 16) ^ ((ln15 & 7) << 4)));
#pragma unroll
    for (int mt = 0; mt < 2; ++mt)
#pragma unroll
      for (int dt = 0; dt < 4; ++dt) {
        acc[mt][dt] = mfma16(vf[dt][0], pb[mt][0], acc[mt][dt]);
        acc[mt][dt] = mfma16(vf[dt][1], pb[mt][1], acc[mt][dt]);
      }
  }

  // 4-way merge (single barrier); Zs rows = q (stride 68 floats)
  if (wv > 0) {
#pragma unroll
    for (int mt = 0; mt < 2; ++mt) {
#pragma unroll
      for (int dt = 0; dt < 4; ++dt)
        *(f32x4*)&Zs[wv - 1][mt][ln15 * 68 + dt * 16 + 4 * g] = acc[mt][dt];
      if (g == 0) {
        Ml[wv - 1][mt][ln15][0] = m_[mt];
        Ml[wv - 1][mt][ln15][1] = l_[mt];
      }
    }
  }
  __syncthreads();
  if (wv == 0) {
#pragma unroll
    for (int mt = 0; mt < 2; ++mt) {
      float mm = m_[mt];
#pragma unroll
      for (int w = 0; w < 3; ++w) mm = fmaxf(mm, Ml[w][mt][ln15][0]);
      const float e0 = __expf(m_[mt] - mm);
      float lsum = l_[mt] * e0;
      float ew[3];
#pragma unroll
      for (int w = 0; w < 3; ++w) {
        ew[w] = __expf(Ml[w][mt][ln15][0] - mm);
        lsum += Ml[w][mt][ln15][1] * ew[w];
      }
      const float inv = 1.0f / lsum;
      float* ob = out + (bT + r0 + mt * 16 + ln15) * 64;
#pragma unroll
      for (int dt = 0; dt < 4; ++dt) {
        f32x4 z;
#pragma unroll
        for (int i = 0; i < 4; ++i) {
          float zz = acc[mt][dt][i] * e0;
#pragma unroll
          for (int w = 0; w < 3; ++w)
            zz += Zs[w][mt][ln15 * 68 + dt * 16 + 4 * g + i] * ew[w];
          z[i] = zz * inv;
        }
        *(f32x4*)&ob[dt * 16 + 4 * g] = z;
      }
    }
  }
}

// ---------------------------------------------------------------------------
extern "C" void kernel_launch(void* const* d_in, const int* in_sizes, int n_in,
                              void* d_out, int out_size, void* d_ws, size_t ws_size,
                              hipStream_t stream)
{
  const float* x  = (const float*)d_in[0];
  const float* Wq = (const float*)d_in[1];
  const float* bq = (const float*)d_in[2];
  const float* Wk = (const float*)d_in[3];
  const float* bk = (const float*)d_in[4];
  const float* Wv = (const float*)d_in[5];
  const float* bv = (const float*)d_in[6];
  float* out = (float*)d_out;

  char* ws = (char*)d_ws;
  unsigned short* Wt  = (unsigned short*)(ws);                      // 384 KB
  unsigned short* Qb  = (unsigned short*)(ws + (1u << 19));         // 2 MB
  unsigned short* Kb  = (unsigned short*)(ws + (1u << 19) + (1u << 21));
  unsigned short* VTb = (unsigned short*)(ws + (1u << 19) + (2u << 21));

  prep_w<<<48, 256, 0, stream>>>(Wq, Wk, Wv, Wt);
  qkv_proj_mfma<<<256, 256, 0, stream>>>(x, Wt, bq, bk, bv, Qb, Kb, VTb);
  attn_flash<<<512, 256, 0, stream>>>(Qb, Kb, VTb, out);
}

// Round 12
// 53.215 us; speedup vs baseline: 1.2931x; 1.0098x over previous
//
#include <hip/hip_runtime.h>
#include <hip/hip_bf16.h>
#include <cstdint>
#include <cstddef>

typedef __attribute__((ext_vector_type(8))) short bf16x8;
typedef __attribute__((ext_vector_type(4))) float f32x4;
typedef __attribute__((ext_vector_type(4))) unsigned int u32x4;

#define T_DIM 2048
#define C_DIM 1024
#define B_DIM 8
#define NEG_BIG (-3.0e38f)

__device__ __forceinline__ unsigned short f2bf(float f) {
  union { __hip_bfloat16 h; unsigned short u; } cv;
  cv.h = __float2bfloat16(f);
  return cv.u;
}
__device__ __forceinline__ f32x4 mfma16(bf16x8 a, bf16x8 b, f32x4 c) {
  return __builtin_amdgcn_mfma_f32_16x16x32_bf16(a, b, c, 0, 0, 0);
}

// ---------------------------------------------------------------------------
// prep_w: W [1024][64] f32 -> Wt [3][64][1024] bf16 (transposed; Wq scaled 1/8)
// (unchanged)
// ---------------------------------------------------------------------------
__global__ __launch_bounds__(256) void prep_w(
    const float* __restrict__ Wq, const float* __restrict__ Wk,
    const float* __restrict__ Wv, unsigned short* __restrict__ Wt)
{
  const int mtx = blockIdx.x >> 4;
  const int k0  = (blockIdx.x & 15) * 64;
  const float* W = (mtx == 0) ? Wq : ((mtx == 1) ? Wk : Wv);
  const float scale = (mtx == 0) ? 0.125f : 1.0f;
  __shared__ float Ws[64][65];
  const int t = threadIdx.x;
#pragma unroll
  for (int j = 0; j < 4; ++j) {
    int r = (t >> 4) + 16 * j;
    int c = (t & 15) * 4;
    union { float4 f4; float f[4]; } uv;
    uv.f4 = *(const float4*)&W[(size_t)(k0 + r) * 64 + c];
#pragma unroll
    for (int jj = 0; jj < 4; ++jj) Ws[c + jj][r] = uv.f[jj] * scale;
  }
  __syncthreads();
#pragma unroll
  for (int q = 0; q < 2; ++q) {
    int g_ = t + 256 * q;
    int d  = g_ >> 3;
    int ko = (g_ & 7) * 8;
    union { unsigned short u[8]; u32x4 v; } pk;
#pragma unroll
    for (int jj = 0; jj < 8; ++jj) pk.u[jj] = f2bf(Ws[d][ko + jj]);
    *(u32x4*)&Wt[((size_t)mtx * 64 + d) * C_DIM + k0 + ko] = pk.v;
  }
}

// ---------------------------------------------------------------------------
// qkv_proj_mfma: round-10 pipeline, now 512 blocks x 32 rows (2 blocks/CU,
// 2 waves/SIMD TLP). Cooperative X staging (no per-wave redundancy), loads
// in flight across each barrier. W restaged per block (2x L2 traffic,
// ~5.7us aggregate at 34.5 TB/s — absorbed).
// ---------------------------------------------------------------------------
__global__ __launch_bounds__(256) void qkv_proj_mfma(
    const float* __restrict__ x,
    const unsigned short* __restrict__ Wt,
    const float* __restrict__ bq, const float* __restrict__ bk, const float* __restrict__ bv,
    unsigned short* __restrict__ Qb, unsigned short* __restrict__ Kb,
    unsigned short* __restrict__ VTb)
{
  __shared__ __align__(16) short Xs[2][32 * 64];       // 4 KB each
  __shared__ __align__(16) short Wsb[2][3 * 64 * 64];  // 24 KB each
  __shared__ __align__(16) unsigned short VTs[64 * 40];// 64 d x 32 t (pad 40)

  const int tid = threadIdx.x;
  const int wv = tid >> 6, lane = tid & 63, g = lane >> 4, ln15 = lane & 15;
  const size_t m0 = (size_t)blockIdx.x * 32;

  f32x4 acc[2][3];
#pragma unroll
  for (int mt = 0; mt < 2; ++mt)
#pragma unroll
    for (int j = 0; j < 3; ++j) acc[mt][j] = (f32x4){0.f, 0.f, 0.f, 0.f};

  float4 xA[2], xB[2];
  u32x4 wr[6];

  auto issueX = [&](float4 (&xr)[2], int kt) {
    if (kt >= 16) return;
#pragma unroll
    for (int q = 0; q < 2; ++q) {
      int g_ = tid + 256 * q;             // 0..511 granules (32 rows x 16)
      int r = g_ >> 4, c4 = (g_ & 15) * 4;
      xr[q] = *(const float4*)&x[(m0 + r) * C_DIM + kt * 64 + c4];
    }
  };
  auto issueW = [&](int kt) {
    if (kt >= 16) return;
#pragma unroll
    for (int mt = 0; mt < 3; ++mt)
#pragma unroll
      for (int q = 0; q < 2; ++q) {
        int g_ = tid + 256 * q;
        int d = g_ >> 3, ko = (g_ & 7) * 8;
        wr[mt * 2 + q] = *(const u32x4*)&Wt[((size_t)mt * 64 + d) * C_DIM + kt * 64 + ko];
      }
  };
  auto writeXb = [&](int nb, const float4 (&xr)[2]) {
#pragma unroll
    for (int q = 0; q < 2; ++q) {
      int g_ = tid + 256 * q;
      int r = g_ >> 4, c4 = (g_ & 15) * 4;
      const float* f = (const float*)&xr[q];
      union { unsigned short u[4]; unsigned long long ll; } pk;
#pragma unroll
      for (int jj = 0; jj < 4; ++jj) pk.u[jj] = f2bf(f[jj]);
      *(unsigned long long*)((char*)Xs[nb] + r * 128 + ((c4 * 2) ^ ((r & 7) << 4))) = pk.ll;
    }
  };
  auto writeWb = [&](int nb) {
#pragma unroll
    for (int mt = 0; mt < 3; ++mt)
#pragma unroll
      for (int q = 0; q < 2; ++q) {
        int g_ = tid + 256 * q;
        int d = g_ >> 3, ko = (g_ & 7) * 8;
        *(u32x4*)((char*)Wsb[nb] + mt * 8192 + d * 128 + ((ko * 2) ^ ((d & 7) << 4))) = wr[mt * 2 + q];
      }
  };
  auto compute = [&](int nb) {
#pragma unroll
    for (int kc = 0; kc < 2; ++kc) {
      bf16x8 a[2];
#pragma unroll
      for (int mt = 0; mt < 2; ++mt) {
        int xr = mt * 16 + ln15;
        a[mt] = *(const bf16x8*)((const char*)Xs[nb] + xr * 128 + ((kc * 64 + g * 16) ^ ((xr & 7) << 4)));
      }
#pragma unroll
      for (int j = 0; j < 3; ++j) {
        int ntg = wv * 3 + j;
        int mtx = ntg >> 2, nc = (ntg & 3) * 16;
        int wrow = nc + ln15;
        bf16x8 bb = *(const bf16x8*)((const char*)Wsb[nb] + mtx * 8192 + wrow * 128 + ((kc * 64 + g * 16) ^ ((wrow & 7) << 4)));
#pragma unroll
        for (int mt = 0; mt < 2; ++mt)
          acc[mt][j] = mfma16(a[mt], bb, acc[mt][j]);
      }
    }
  };

  issueX(xA, 0); issueW(0);
  writeXb(0, xA); writeWb(0);
  issueX(xB, 1);
  __syncthreads();

  for (int kt = 0; kt < 16; kt += 2) {
    issueW(kt + 1);
    issueX(xA, kt + 2);
    compute(0);
    if (kt + 1 < 16) { writeXb(1, xB); writeWb(1); }
    __syncthreads();
    if (kt + 1 < 16) {
      issueW(kt + 2);
      issueX(xB, kt + 3);
      compute(1);
      if (kt + 2 < 16) { writeXb(0, xA); writeWb(0); }
      __syncthreads();
    }
  }

  // epilogue: Q/K direct; V -> LDS transpose tile -> coalesced VTb
#pragma unroll
  for (int j = 0; j < 3; ++j) {
    int ntg = wv * 3 + j;
    int mtx = ntg >> 2, nc = (ntg & 3) * 16;
    if (mtx < 2) {
      const float* bias = (mtx == 0) ? bq : bk;
      unsigned short* Out = (mtx == 0) ? Qb : Kb;
      float bvv = bias[nc + ln15] * ((mtx == 0) ? 0.125f : 1.0f);
#pragma unroll
      for (int mt = 0; mt < 2; ++mt)
#pragma unroll
        for (int i = 0; i < 4; ++i)
          Out[(m0 + mt * 16 + 4 * g + i) * 64 + nc + ln15] = f2bf(acc[mt][j][i] + bvv);
    } else {
      float bvv = bv[nc + ln15];
#pragma unroll
      for (int mt = 0; mt < 2; ++mt)
#pragma unroll
        for (int i = 0; i < 4; ++i)
          VTs[(nc + ln15) * 40 + mt * 16 + 4 * g + i] = f2bf(acc[mt][j][i] + bvv);
    }
  }
  __syncthreads();
  {
    int d = tid >> 2, t8 = (tid & 3) * 8;  // 64 d-rows x 32 t-cols
    u32x4 v0 = *(const u32x4*)&VTs[d * 40 + t8];
    size_t b = m0 >> 11, tloc = m0 & 2047;
    *(u32x4*)&VTb[(b * 64 + d) * T_DIM + tloc + t8] = v0;
  }
}

// ---------------------------------------------------------------------------
// attn_flash: round-11 swapped-operand version, UNCHANGED (~29 us).
// ---------------------------------------------------------------------------
__global__ __launch_bounds__(256) void attn_flash(
    const unsigned short* __restrict__ Qb,   // [B*T][64] (pre-scaled 1/8)
    const unsigned short* __restrict__ Kb,   // [B*T][64]
    const unsigned short* __restrict__ VTb,  // [B][64][T]
    float* __restrict__ out)                 // [B*T][64] f32
{
  __shared__ __align__(16) short Ps[4][2 * 16 * 64];
  __shared__ __align__(16) float Zs[3][2][16 * 68];
  __shared__ float Ml[3][2][16][2];

  const int tid  = threadIdx.x;
  const int wv   = tid >> 6;
  const int lane = tid & 63;
  const int g    = lane >> 4;
  const int ln15 = lane & 15;

  const int qt = 63 - (blockIdx.x >> 3);
  const int b  = blockIdx.x & 7;
  const int r0 = qt * 32;
  const int ntiles = (qt >> 1) + 1;

  const size_t bT = (size_t)b * T_DIM;

  bf16x8 qa[2][2];
#pragma unroll
  for (int mt = 0; mt < 2; ++mt) {
    const unsigned short* qp = Qb + (bT + r0 + mt * 16 + ln15) * 64 + g * 8;
    qa[mt][0] = *(const bf16x8*)qp;
    qa[mt][1] = *(const bf16x8*)(qp + 32);
  }

  f32x4 acc[2][4];
#pragma unroll
  for (int mt = 0; mt < 2; ++mt)
#pragma unroll
    for (int dt = 0; dt < 4; ++dt) acc[mt][dt] = (f32x4){0.f, 0.f, 0.f, 0.f};
  float m_[2], l_[2];
#pragma unroll
  for (int mt = 0; mt < 2; ++mt) { m_[mt] = NEG_BIG; l_[mt] = 0.f; }

  char* myP = (char*)Ps[wv];

  for (int it = wv; it < ntiles; it += 4) {
    const int s0 = it * 64;
    bf16x8 kf[4][2];
#pragma unroll
    for (int nt = 0; nt < 4; ++nt) {
      const unsigned short* kp = Kb + (bT + s0 + nt * 16 + ln15) * 64 + g * 8;
      kf[nt][0] = *(const bf16x8*)kp;
      kf[nt][1] = *(const bf16x8*)(kp + 32);
    }
    bf16x8 vf[4][2];
#pragma unroll
    for (int dt = 0; dt < 4; ++dt) {
      const unsigned short* vp = VTb + ((size_t)b * 64 + dt * 16 + ln15) * T_DIM + s0 + g * 8;
      vf[dt][0] = *(const bf16x8*)vp;
      vf[dt][1] = *(const bf16x8*)(vp + 32);
    }
    f32x4 st[2][4];
#pragma unroll
    for (int mt = 0; mt < 2; ++mt)
#pragma unroll
      for (int nt = 0; nt < 4; ++nt) {
        f32x4 a = (f32x4){0.f, 0.f, 0.f, 0.f};
        a = mfma16(kf[nt][0], qa[mt][0], a);
        a = mfma16(kf[nt][1], qa[mt][1], a);
        st[mt][nt] = a;
      }
    if (s0 + 63 > r0) {
#pragma unroll
      for (int mt = 0; mt < 2; ++mt) {
        const int qg = r0 + mt * 16 + ln15;
#pragma unroll
        for (int nt = 0; nt < 4; ++nt) {
          const int kvb = s0 + nt * 16 + 4 * g;
#pragma unroll
          for (int i = 0; i < 4; ++i)
            if (kvb + i > qg) st[mt][nt][i] = NEG_BIG;
        }
      }
    }
#pragma unroll
    for (int mt = 0; mt < 2; ++mt) {
      f32x4 t4;
#pragma unroll
      for (int i = 0; i < 4; ++i)
        t4[i] = fmaxf(fmaxf(st[mt][0][i], st[mt][1][i]), fmaxf(st[mt][2][i], st[mt][3][i]));
      float mx = fmaxf(fmaxf(t4[0], t4[1]), fmaxf(t4[2], t4[3]));
      mx = fmaxf(mx, __shfl_xor(mx, 16));
      mx = fmaxf(mx, __shfl_xor(mx, 32));
      const float mn = fmaxf(m_[mt], mx);
      const float corr = __expf(m_[mt] - mn);
      m_[mt] = mn;
#pragma unroll
      for (int nt = 0; nt < 4; ++nt)
#pragma unroll
        for (int i = 0; i < 4; ++i)
          st[mt][nt][i] = __expf(st[mt][nt][i] - mn);
      float ps = 0.f;
#pragma unroll
      for (int nt = 0; nt < 4; ++nt)
        ps += (st[mt][nt][0] + st[mt][nt][1]) + (st[mt][nt][2] + st[mt][nt][3]);
      ps += __shfl_xor(ps, 16);
      ps += __shfl_xor(ps, 32);
      l_[mt] = l_[mt] * corr + ps;
#pragma unroll
      for (int dt = 0; dt < 4; ++dt)
#pragma unroll
        for (int i = 0; i < 4; ++i)
          acc[mt][dt][i] *= corr;
#pragma unroll
      for (int nt = 0; nt < 4; ++nt) {
        unsigned int lo = (unsigned int)f2bf(st[mt][nt][0]) | ((unsigned int)f2bf(st[mt][nt][1]) << 16);
        unsigned int hi = (unsigned int)f2bf(st[mt][nt][2]) | ((unsigned int)f2bf(st[mt][nt][3]) << 16);
        *(unsigned long long*)(myP + mt * 2048 + ln15 * 128 +
                               ((nt * 32 + g * 8) ^ ((ln15 & 7) << 4))) =
            ((unsigned long long)hi << 32) | lo;
      }
    }
    bf16x8 pb[2][2];
#pragma unroll
    for (int mt = 0; mt < 2; ++mt)
#pragma unroll
      for (int kc = 0; kc < 2; ++kc)
        pb[mt][kc] = *(const bf16x8*)(myP + mt * 2048 + ln15 * 128 +
                                      ((kc * 64 + g * 16) ^ ((ln15 & 7) << 4)));
#pragma unroll
    for (int mt = 0; mt < 2; ++mt)
#pragma unroll
      for (int dt = 0; dt < 4; ++dt) {
        acc[mt][dt] = mfma16(vf[dt][0], pb[mt][0], acc[mt][dt]);
        acc[mt][dt] = mfma16(vf[dt][1], pb[mt][1], acc[mt][dt]);
      }
  }

  if (wv > 0) {
#pragma unroll
    for (int mt = 0; mt < 2; ++mt) {
#pragma unroll
      for (int dt = 0; dt < 4; ++dt)
        *(f32x4*)&Zs[wv - 1][mt][ln15 * 68 + dt * 16 + 4 * g] = acc[mt][dt];
      if (g == 0) {
        Ml[wv - 1][mt][ln15][0] = m_[mt];
        Ml[wv - 1][mt][ln15][1] = l_[mt];
      }
    }
  }
  __syncthreads();
  if (wv == 0) {
#pragma unroll
    for (int mt = 0; mt < 2; ++mt) {
      float mm = m_[mt];
#pragma unroll
      for (int w = 0; w < 3; ++w) mm = fmaxf(mm, Ml[w][mt][ln15][0]);
      const float e0 = __expf(m_[mt] - mm);
      float lsum = l_[mt] * e0;
      float ew[3];
#pragma unroll
      for (int w = 0; w < 3; ++w) {
        ew[w] = __expf(Ml[w][mt][ln15][0] - mm);
        lsum += Ml[w][mt][ln15][1] * ew[w];
      }
      const float inv = 1.0f / lsum;
      float* ob = out + (bT + r0 + mt * 16 + ln15) * 64;
#pragma unroll
      for (int dt = 0; dt < 4; ++dt) {
        f32x4 z;
#pragma unroll
        for (int i = 0; i < 4; ++i) {
          float zz = acc[mt][dt][i] * e0;
#pragma unroll
          for (int w = 0; w < 3; ++w)
            zz += Zs[w][mt][ln15 * 68 + dt * 16 + 4 * g + i] * ew[w];
          z[i] = zz * inv;
        }
        *(f32x4*)&ob[dt * 16 + 4 * g] = z;
      }
    }
  }
}

// ---------------------------------------------------------------------------
extern "C" void kernel_launch(void* const* d_in, const int* in_sizes, int n_in,
                              void* d_out, int out_size, void* d_ws, size_t ws_size,
                              hipStream_t stream)
{
  const float* x  = (const float*)d_in[0];
  const float* Wq = (const float*)d_in[1];
  const float* bq = (const float*)d_in[2];
  const float* Wk = (const float*)d_in[3];
  const float* bk = (const float*)d_in[4];
  const float* Wv = (const float*)d_in[5];
  const float* bv = (const float*)d_in[6];
  float* out = (float*)d_out;

  char* ws = (char*)d_ws;
  unsigned short* Wt  = (unsigned short*)(ws);                      // 384 KB
  unsigned short* Qb  = (unsigned short*)(ws + (1u << 19));         // 2 MB
  unsigned short* Kb  = (unsigned short*)(ws + (1u << 19) + (1u << 21));
  unsigned short* VTb = (unsigned short*)(ws + (1u << 19) + (2u << 21));

  prep_w<<<48, 256, 0, stream>>>(Wq, Wk, Wv, Wt);
  qkv_proj_mfma<<<512, 256, 0, stream>>>(x, Wt, bq, bk, bv, Qb, Kb, VTb);
  attn_flash<<<512, 256, 0, stream>>>(Qb, Kb, VTb, out);
}